// Round 3
// baseline (719.202 us; speedup 1.0000x reference)
//
#include <hip/hip_runtime.h>

#define TOK 16384
#define DD 1024
#define HH 2048
#define AA 128
#define EE 8
#define SS 2048
#define BB 8

typedef __attribute__((ext_vector_type(8))) short short8;
typedef __attribute__((ext_vector_type(4))) float floatx4;
typedef __attribute__((address_space(1))) const void glob_cvoid;
typedef __attribute__((address_space(3))) void lds_void;

__device__ __forceinline__ unsigned short f2b(float f) {
  unsigned u = __float_as_uint(f);
  u += 0x7fff + ((u >> 16) & 1);          // RNE
  return (unsigned short)(u >> 16);
}
__device__ __forceinline__ float b2f(unsigned short h) {
  return __uint_as_float(((unsigned)h) << 16);
}

// ---------------- elementwise f32 -> bf16 cast ----------------
__global__ void cast_f32_bf16(const float* __restrict__ in, unsigned short* __restrict__ out, long n4) {
  long i = (long)blockIdx.x * blockDim.x + threadIdx.x;
  const long stride = (long)gridDim.x * blockDim.x;
  for (; i < n4; i += stride) {
    float4 v = ((const float4*)in)[i];
    ushort4 o;
    o.x = f2b(v.x); o.y = f2b(v.y); o.z = f2b(v.z); o.w = f2b(v.w);
    ((ushort4*)out)[i] = o;
  }
}

// ---------------- transpose+cast: in[R,C] f32 -> out[C,R] bf16 ----------------
__global__ void transpose_cast(const float* __restrict__ in, unsigned short* __restrict__ out,
                               int R, int C) {
  __shared__ float t[32][33];
  const int lx = threadIdx.x & 31, ly = threadIdx.x >> 5;   // 32x8
  const int r0 = blockIdx.y * 32, c0 = blockIdx.x * 32;
#pragma unroll
  for (int i = 0; i < 32; i += 8)
    t[ly + i][lx] = in[(long)(r0 + ly + i) * C + (c0 + lx)];
  __syncthreads();
#pragma unroll
  for (int i = 0; i < 32; i += 8)
    out[(long)(c0 + ly + i) * R + (r0 + lx)] = f2b(t[lx][ly + i]);
}

// ---------------- MFMA GEMM: C[M,N] = A[M,K] @ Bt[N,K]^T, bf16 in, fp32 acc ----------------
// 128x128 tile, BK=64, 256 thr (4 waves in 2x2), XOR-swizzled LDS, global_load_lds w=16.
// EPI: 0 f32 | 3 bf16 | 4 clip+-5,silu->bf16 | 6 0.1*v->bf16
template<int EPI>
__global__ __launch_bounds__(256)
void gemm_bt(const unsigned short* __restrict__ Ag, long sAz, int lda,
             const unsigned short* __restrict__ Bg, long sBz, int ldb,
             void* __restrict__ Cg, long sCz, int ldc,
             int K)
{
  __shared__ __align__(16) short As[128*64];
  __shared__ __align__(16) short Bs[128*64];
  const int tid  = threadIdx.x;
  const int lane = tid & 63, wave = tid >> 6;
  const int q = lane >> 4, l15 = lane & 15, l7 = lane & 7;
  const int wm = wave & 1, wn = wave >> 1;

  const int arow = tid >> 3;                       // 0..31
  const int kc8  = ((tid & 7) ^ (arow & 7)) * 8;   // element offset within BK tile

  const short* Ap = (const short*)Ag + (long)blockIdx.z*sAz + (long)(blockIdx.y*128 + arow)*lda + kc8;
  const short* Bp = (const short*)Bg + (long)blockIdx.z*sBz + (long)(blockIdx.x*128 + arow)*ldb + kc8;
  char* AsW = (char*)As + wave*1024;
  char* BsW = (char*)Bs + wave*1024;

  floatx4 acc[4][4] = {};

  for (int kt = 0; kt < K; kt += 64) {
    __syncthreads();
#pragma unroll
    for (int i = 0; i < 4; ++i) {
      __builtin_amdgcn_global_load_lds((glob_cvoid*)(Ap + (long)i*32*lda + kt),
                                       (lds_void*)(AsW + i*4096), 16, 0, 0);
      __builtin_amdgcn_global_load_lds((glob_cvoid*)(Bp + (long)i*32*ldb + kt),
                                       (lds_void*)(BsW + i*4096), 16, 0, 0);
    }
    __syncthreads();
#pragma unroll
    for (int s = 0; s < 2; ++s) {
      short8 af[4], bf[4];
      const int slotoff = ((s*4 + q) ^ l7) * 16;
#pragma unroll
      for (int i = 0; i < 4; ++i) {
        af[i] = *(const short8*)((const char*)As + (wm*64 + i*16 + l15)*128 + slotoff);
        bf[i] = *(const short8*)((const char*)Bs + (wn*64 + i*16 + l15)*128 + slotoff);
      }
#pragma unroll
      for (int i = 0; i < 4; ++i)
#pragma unroll
        for (int j = 0; j < 4; ++j)
          acc[i][j] = __builtin_amdgcn_mfma_f32_16x16x32_bf16(af[i], bf[j], acc[i][j], 0, 0, 0);
    }
  }

  const long cz = (long)blockIdx.z * sCz;
#pragma unroll
  for (int i = 0; i < 4; ++i)
#pragma unroll
    for (int j = 0; j < 4; ++j)
#pragma unroll
      for (int r = 0; r < 4; ++r) {
        const int row = blockIdx.y*128 + wm*64 + i*16 + q*4 + r;
        const int col = blockIdx.x*128 + wn*64 + j*16 + l15;
        const long ci = cz + (long)row*ldc + col;
        float v = acc[i][j][r];
        if (EPI == 0) {
          ((float*)Cg)[ci] = v;
        } else if (EPI == 3) {
          ((unsigned short*)Cg)[ci] = f2b(v);
        } else if (EPI == 4) {
          v = fminf(fmaxf(v, -5.f), 5.f);
          v = v / (1.f + __expf(-v));
          ((unsigned short*)Cg)[ci] = f2b(v);
        } else if (EPI == 6) {
          ((unsigned short*)Cg)[ci] = f2b(0.1f * v);
        }
      }
}

// ---------------- fused gate+up GEMM: hid = silu(x@wg^T) * (x@wu^T) ----------------
__global__ __launch_bounds__(256)
void gemm_gateup(const unsigned short* __restrict__ xg,
                 const unsigned short* __restrict__ wg,
                 const unsigned short* __restrict__ wu,
                 unsigned short* __restrict__ hidp)
{
  __shared__ __align__(16) short As[128*64];
  __shared__ __align__(16) short Gs[128*64];
  __shared__ __align__(16) short Us[128*64];
  const int tid  = threadIdx.x;
  const int lane = tid & 63, wave = tid >> 6;
  const int q = lane >> 4, l15 = lane & 15, l7 = lane & 7;
  const int wm = wave & 1, wn = wave >> 1;
  const int arow = tid >> 3;
  const int kc8  = ((tid & 7) ^ (arow & 7)) * 8;

  const short* Ap = (const short*)xg + (long)(blockIdx.y*128 + arow)*DD + kc8;
  const short* Gp = (const short*)wg + (long)(blockIdx.x*128 + arow)*DD + kc8;
  const short* Up = (const short*)wu + (long)(blockIdx.x*128 + arow)*DD + kc8;
  char* AsW = (char*)As + wave*1024;
  char* GsW = (char*)Gs + wave*1024;
  char* UsW = (char*)Us + wave*1024;

  floatx4 accg[4][4] = {}, accu[4][4] = {};

  for (int kt = 0; kt < DD; kt += 64) {
    __syncthreads();
#pragma unroll
    for (int i = 0; i < 4; ++i) {
      __builtin_amdgcn_global_load_lds((glob_cvoid*)(Ap + (long)i*32*DD + kt),
                                       (lds_void*)(AsW + i*4096), 16, 0, 0);
      __builtin_amdgcn_global_load_lds((glob_cvoid*)(Gp + (long)i*32*DD + kt),
                                       (lds_void*)(GsW + i*4096), 16, 0, 0);
      __builtin_amdgcn_global_load_lds((glob_cvoid*)(Up + (long)i*32*DD + kt),
                                       (lds_void*)(UsW + i*4096), 16, 0, 0);
    }
    __syncthreads();
#pragma unroll
    for (int s = 0; s < 2; ++s) {
      short8 af[4], bf[4];
      const int slotoff = ((s*4 + q) ^ l7) * 16;
#pragma unroll
      for (int i = 0; i < 4; ++i)
        af[i] = *(const short8*)((const char*)As + (wm*64 + i*16 + l15)*128 + slotoff);
#pragma unroll
      for (int i = 0; i < 4; ++i)
        bf[i] = *(const short8*)((const char*)Gs + (wn*64 + i*16 + l15)*128 + slotoff);
#pragma unroll
      for (int i = 0; i < 4; ++i)
#pragma unroll
        for (int j = 0; j < 4; ++j)
          accg[i][j] = __builtin_amdgcn_mfma_f32_16x16x32_bf16(af[i], bf[j], accg[i][j], 0, 0, 0);
#pragma unroll
      for (int i = 0; i < 4; ++i)
        bf[i] = *(const short8*)((const char*)Us + (wn*64 + i*16 + l15)*128 + slotoff);
#pragma unroll
      for (int i = 0; i < 4; ++i)
#pragma unroll
        for (int j = 0; j < 4; ++j)
          accu[i][j] = __builtin_amdgcn_mfma_f32_16x16x32_bf16(af[i], bf[j], accu[i][j], 0, 0, 0);
    }
  }

#pragma unroll
  for (int i = 0; i < 4; ++i)
#pragma unroll
    for (int j = 0; j < 4; ++j)
#pragma unroll
      for (int r = 0; r < 4; ++r) {
        const int row = blockIdx.y*128 + wm*64 + i*16 + q*4 + r;
        const int col = blockIdx.x*128 + wn*64 + j*16 + l15;
        float g = accg[i][j][r], u = accu[i][j][r];
        float hv = g / (1.f + __expf(-g)) * u;
        hidp[(long)row*HH + col] = f2b(hv);
      }
}

// ---------------- fused final GEMM: out = hid@wdb^T + Fc@Wc'^T (Wc' pre-scaled 0.1) ----------------
__global__ __launch_bounds__(256)
void gemm_final(const unsigned short* __restrict__ hidp,
                const unsigned short* __restrict__ wdbp,
                const unsigned short* __restrict__ Fcp,
                const unsigned short* __restrict__ Wcp,
                float* __restrict__ outp)
{
  __shared__ __align__(16) short As[128*64];
  __shared__ __align__(16) short Bs[128*64];
  const int tid  = threadIdx.x;
  const int lane = tid & 63, wave = tid >> 6;
  const int q = lane >> 4, l15 = lane & 15, l7 = lane & 7;
  const int wm = wave & 1, wn = wave >> 1;
  const int arow = tid >> 3;
  const int kc8  = ((tid & 7) ^ (arow & 7)) * 8;
  char* AsW = (char*)As + wave*1024;
  char* BsW = (char*)Bs + wave*1024;

  floatx4 acc[4][4] = {};

  // phase 1: hid @ wdb^T, K = HH
  {
    const short* Ap = (const short*)hidp + (long)(blockIdx.y*128 + arow)*HH + kc8;
    const short* Bp = (const short*)wdbp + (long)(blockIdx.x*128 + arow)*HH + kc8;
    for (int kt = 0; kt < HH; kt += 64) {
      __syncthreads();
#pragma unroll
      for (int i = 0; i < 4; ++i) {
        __builtin_amdgcn_global_load_lds((glob_cvoid*)(Ap + (long)i*32*HH + kt),
                                         (lds_void*)(AsW + i*4096), 16, 0, 0);
        __builtin_amdgcn_global_load_lds((glob_cvoid*)(Bp + (long)i*32*HH + kt),
                                         (lds_void*)(BsW + i*4096), 16, 0, 0);
      }
      __syncthreads();
#pragma unroll
      for (int s = 0; s < 2; ++s) {
        short8 af[4], bf[4];
        const int slotoff = ((s*4 + q) ^ l7) * 16;
#pragma unroll
        for (int i = 0; i < 4; ++i) {
          af[i] = *(const short8*)((const char*)As + (wm*64 + i*16 + l15)*128 + slotoff);
          bf[i] = *(const short8*)((const char*)Bs + (wn*64 + i*16 + l15)*128 + slotoff);
        }
#pragma unroll
        for (int i = 0; i < 4; ++i)
#pragma unroll
          for (int j = 0; j < 4; ++j)
            acc[i][j] = __builtin_amdgcn_mfma_f32_16x16x32_bf16(af[i], bf[j], acc[i][j], 0, 0, 0);
      }
    }
  }
  // phase 2: Fc @ Wc'^T, K = 256
  {
    const short* Ap = (const short*)Fcp + (long)(blockIdx.y*128 + arow)*256 + kc8;
    const short* Bp = (const short*)Wcp + (long)(blockIdx.x*128 + arow)*256 + kc8;
    for (int kt = 0; kt < 256; kt += 64) {
      __syncthreads();
#pragma unroll
      for (int i = 0; i < 4; ++i) {
        __builtin_amdgcn_global_load_lds((glob_cvoid*)(Ap + (long)i*32*256 + kt),
                                         (lds_void*)(AsW + i*4096), 16, 0, 0);
        __builtin_amdgcn_global_load_lds((glob_cvoid*)(Bp + (long)i*32*256 + kt),
                                         (lds_void*)(BsW + i*4096), 16, 0, 0);
      }
      __syncthreads();
#pragma unroll
      for (int s = 0; s < 2; ++s) {
        short8 af[4], bf[4];
        const int slotoff = ((s*4 + q) ^ l7) * 16;
#pragma unroll
        for (int i = 0; i < 4; ++i) {
          af[i] = *(const short8*)((const char*)As + (wm*64 + i*16 + l15)*128 + slotoff);
          bf[i] = *(const short8*)((const char*)Bs + (wn*64 + i*16 + l15)*128 + slotoff);
        }
#pragma unroll
        for (int i = 0; i < 4; ++i)
#pragma unroll
          for (int j = 0; j < 4; ++j)
            acc[i][j] = __builtin_amdgcn_mfma_f32_16x16x32_bf16(af[i], bf[j], acc[i][j], 0, 0, 0);
      }
    }
  }

#pragma unroll
  for (int i = 0; i < 4; ++i)
#pragma unroll
    for (int j = 0; j < 4; ++j)
#pragma unroll
      for (int r = 0; r < 4; ++r) {
        const int row = blockIdx.y*128 + wm*64 + i*16 + q*4 + r;
        const int col = blockIdx.x*128 + wn*64 + j*16 + l15;
        outp[(long)row*DD + col] = acc[i][j][r];
      }
}

// ---------------- LayerNorm over A=128 (one wave per row) ----------------
__global__ void ln_rows(const float* __restrict__ X, const float* __restrict__ g,
                        const float* __restrict__ b, unsigned short* __restrict__ lnout,
                        unsigned short* __restrict__ rawout, unsigned short* __restrict__ tout)
{
  const int lane = threadIdx.x & 63, wave = threadIdx.x >> 6;
  const long t = (long)blockIdx.x*4 + wave;
  const float* x = X + t*AA;
  float x0 = x[lane], x1 = x[lane + 64];
  float s = x0 + x1, s2 = x0*x0 + x1*x1;
#pragma unroll
  for (int m = 1; m < 64; m <<= 1) {
    s  += __shfl_xor(s, m, 64);
    s2 += __shfl_xor(s2, m, 64);
  }
  float mean = s * (1.f/AA);
  float inv  = rsqrtf(s2*(1.f/AA) - mean*mean + 1e-5f);
  float y0 = (x0 - mean)*inv*g[lane] + b[lane];
  float y1 = (x1 - mean)*inv*g[lane+64] + b[lane+64];
  lnout[t*AA + lane]      = f2b(y0);
  lnout[t*AA + lane + 64] = f2b(y1);
  if (rawout) { rawout[t*AA+lane] = f2b(x0); rawout[t*AA+lane+64] = f2b(x1); }
  if (tout) {
    const long bb = t >> 11, si = t & (SS-1);
    tout[bb*(long)AA*SS + (long)lane*SS + si]      = f2b(y0);
    tout[bb*(long)AA*SS + (long)(lane+64)*SS + si] = f2b(y1);
  }
}

// ---------------- per-token expert select (last positive wins) + LN ----------------
__global__ void expert_select_ln(const float* __restrict__ ew, const unsigned short* __restrict__ eall,
                                 const float* __restrict__ eg, const float* __restrict__ ebias,
                                 unsigned short* __restrict__ Fc)
{
  const int lane = threadIdx.x & 63, wave = threadIdx.x >> 6;
  const long t = (long)blockIdx.x*4 + wave;
  const float* w = ew + t*EE;
  int ie = -1;
#pragma unroll
  for (int i = 0; i < EE; ++i) if (w[i] > 0.f) ie = i;
  unsigned short o0 = 0, o1 = 0;
  if (ie >= 0) {
    float x0 = b2f(eall[t*(EE*AA) + ie*AA + lane]);
    float x1 = b2f(eall[t*(EE*AA) + ie*AA + lane + 64]);
    float s = x0 + x1, s2 = x0*x0 + x1*x1;
#pragma unroll
    for (int m = 1; m < 64; m <<= 1) { s += __shfl_xor(s, m, 64); s2 += __shfl_xor(s2, m, 64); }
    float mean = s * (1.f/AA);
    float inv  = rsqrtf(s2*(1.f/AA) - mean*mean + 1e-5f);
    o0 = f2b((x0-mean)*inv*eg[ie*AA+lane]    + ebias[ie*AA+lane]);
    o1 = f2b((x1-mean)*inv*eg[ie*AA+lane+64] + ebias[ie*AA+lane+64]);
  }
  Fc[t*256 + lane]      = o0;
  Fc[t*256 + lane + 64] = o1;
}

extern "C" void kernel_launch(void* const* d_in, const int* in_sizes, int n_in,
                              void* d_out, int out_size, void* d_ws, size_t ws_size,
                              hipStream_t stream)
{
  const float* x       = (const float*)d_in[0];
  const float* ew      = (const float*)d_in[1];
  const float* w_up    = (const float*)d_in[2];
  const float* w_gate  = (const float*)d_in[3];
  const float* w_down  = (const float*)d_in[4];
  const float* w_pre   = (const float*)d_in[5];
  const float* w_post  = (const float*)d_in[6];
  const float* an_g    = (const float*)d_in[7];
  const float* an_b    = (const float*)d_in[8];
  const float* w_aproj = (const float*)d_in[9];
  const float* w_exp   = (const float*)d_in[10];
  const float* eln_g   = (const float*)d_in[11];
  const float* eln_b   = (const float*)d_in[12];
  const float* w_eproj = (const float*)d_in[13];
  const float* w_out   = (const float*)d_in[14];

  char* ws = (char*)d_ws;
  size_t off = 0;
  auto take = [&](size_t bytes) { char* p = ws + off; off += (bytes + 255) & ~(size_t)255; return p; };

  // Sc (scores, 64MB) aliases xb (first 32MB) + eall (next 32MB): xb dead after the
  // pre-GEMM, eall dead after expert_select_ln — both strictly before the scores GEMM.
  unsigned short* Sc    = (unsigned short*)take((size_t)BB*SS*SS*2);
  unsigned short* xb    = Sc;
  unsigned short* eall  = (unsigned short*)((char*)Sc + (size_t)TOK*DD*2);
  unsigned short* hid   = (unsigned short*)take((size_t)TOK*HH*2);
  float*          pre   = (float*)take((size_t)TOK*AA*4);
  float*          postA = (float*)take((size_t)TOK*AA*4);
  unsigned short* Fc    = (unsigned short*)take((size_t)TOK*256*2);
  unsigned short* ain   = (unsigned short*)take((size_t)TOK*AA*2);
  unsigned short* ainT  = (unsigned short*)take((size_t)TOK*AA*2);
  unsigned short* aout  = (unsigned short*)take((size_t)TOK*AA*2);
  unsigned short* preb  = (unsigned short*)take((size_t)TOK*AA*2);
  unsigned short* wgb   = (unsigned short*)take((size_t)HH*DD*2);
  unsigned short* wub   = (unsigned short*)take((size_t)HH*DD*2);
  unsigned short* wdb   = (unsigned short*)take((size_t)DD*HH*2);
  unsigned short* wpostb= (unsigned short*)take((size_t)AA*HH*2);
  unsigned short* wpreb = (unsigned short*)take((size_t)AA*DD*2);
  unsigned short* wexpb = (unsigned short*)take((size_t)EE*AA*AA*2);
  unsigned short* Wc    = (unsigned short*)take((size_t)DD*256*2);
  (void)ws_size; (void)in_sizes; (void)n_in; (void)out_size;

  // Fold operands alias hid (hid is first written by gemm_gateup, which runs
  // strictly after the fold GEMM on this stream): w_out_bf16 (4MB) + eproj^T/aproj^T (1MB).
  unsigned short* woutb  = hid;                               // [1024,2048] bf16
  unsigned short* btT    = hid + (size_t)DD*HH;               // [2,128,2048] bf16
  unsigned short* eprojT = btT;
  unsigned short* aprojT = btT + (size_t)AA*HH;

  // casts
  cast_f32_bf16<<<1024, 256, 0, stream>>>(x,      xb,     (long)TOK*DD/4);
  cast_f32_bf16<<<256,  256, 0, stream>>>(w_gate, wgb,    (long)HH*DD/4);
  cast_f32_bf16<<<256,  256, 0, stream>>>(w_up,   wub,    (long)HH*DD/4);
  cast_f32_bf16<<<256,  256, 0, stream>>>(w_down, wdb,    (long)DD*HH/4);
  cast_f32_bf16<<<256,  256, 0, stream>>>(w_out,  woutb,  (long)DD*HH/4);
  cast_f32_bf16<<<64,   256, 0, stream>>>(w_post, wpostb, (long)AA*HH/4);
  cast_f32_bf16<<<32,   256, 0, stream>>>(w_pre,  wpreb,  (long)AA*DD/4);
  cast_f32_bf16<<<32,   256, 0, stream>>>(w_exp,  wexpb,  (long)EE*AA*AA/4);

  // transpose+cast the fold B operands: [H,A] f32 -> [A,H] bf16
  transpose_cast<<<dim3(AA/32, HH/32), 256, 0, stream>>>(w_eproj, eprojT, HH, AA);
  transpose_cast<<<dim3(AA/32, HH/32), 256, 0, stream>>>(w_aproj, aprojT, HH, AA);

  // folded matrices via batched MFMA GEMM, pre-scaled by 0.1 (EPI 6):
  // z=0: 0.1*w_out@w_eproj -> Wc[:,0:128], z=1: 0.1*w_down@w_aproj -> Wc[:,128:256]
  gemm_bt<6><<<dim3(1, DD/128, 2), 256, 0, stream>>>(
      woutb, (long)(wdb - woutb), HH,
      eprojT, (long)AA*HH, HH,
      Wc, AA, 256, HH);

  // fused gate+up: hid = silu(x@wg^T) * (x@wu^T)
  gemm_gateup<<<dim3(HH/128, TOK/128, 1), 256, 0, stream>>>(xb, wgb, wub, hid);

  // pre = x @ w_pre^T (fp32), then LN -> adapt_in (+ raw bf16 + transposed copy)
  gemm_bt<0><<<dim3(1, TOK/128, 1), 256, 0, stream>>>(xb,0,DD, wpreb,0,DD, pre,0,AA, DD);
  ln_rows<<<TOK/4, 256, 0, stream>>>(pre, an_g, an_b, ain, preb, ainT);

  // all-expert mix + per-token select/LN -> Fc[:,0:128]
  gemm_bt<3><<<dim3((EE*AA)/128, TOK/128, 1), 256, 0, stream>>>(preb,0,AA, wexpb,0,AA, eall,0,EE*AA, AA);
  expert_select_ln<<<TOK/4, 256, 0, stream>>>(ew, eall, eln_g, eln_b, Fc);

  // adapt_out = LN(hidden @ w_post^T)
  gemm_bt<0><<<dim3(1, TOK/128, 1), 256, 0, stream>>>(hid,0,HH, wpostb,0,HH, postA,0,AA, HH);
  ln_rows<<<TOK/4, 256, 0, stream>>>(postA, an_g, an_b, aout, nullptr, nullptr);

  // scores: Sc[z] = silu(clip(ain[z] @ aout[z]^T))   (K = A = 128)
  gemm_bt<4><<<dim3(SS/128, SS/128, BB), 256, 0, stream>>>(ain,(long)SS*AA,AA, aout,(long)SS*AA,AA,
                                                           Sc,(long)SS*SS,SS, AA);
  // adapt: Fc[:,128:256] = Sc[z] @ ainT[z]^T
  gemm_bt<3><<<dim3(1, SS/128, BB), 256, 0, stream>>>(Sc,(long)SS*SS,SS, ainT,(long)AA*SS,SS,
                                                      Fc+AA,(long)SS*256,256, SS);
  // out = hid@wdb^T + Fc@Wc'^T  (fp32, Wc' pre-scaled by 0.1)
  gemm_final<<<dim3(DD/128, TOK/128, 1), 256, 0, stream>>>(hid, wdb, Fc, Wc, (float*)d_out);
}

// Round 4
// 653.449 us; speedup vs baseline: 1.1006x; 1.1006x over previous
//
#include <hip/hip_runtime.h>

#define TOK 16384
#define DD 1024
#define HH 2048
#define AA 128
#define EE 8
#define SS 2048
#define BB 8

typedef __attribute__((ext_vector_type(8))) short short8;
typedef __attribute__((ext_vector_type(4))) float floatx4;
typedef __attribute__((address_space(1))) const void glob_cvoid;
typedef __attribute__((address_space(3))) void lds_void;

__device__ __forceinline__ unsigned short f2b(float f) {
  unsigned u = __float_as_uint(f);
  u += 0x7fff + ((u >> 16) & 1);          // RNE
  return (unsigned short)(u >> 16);
}
__device__ __forceinline__ float b2f(unsigned short h) {
  return __uint_as_float(((unsigned)h) << 16);
}

// XCD-affinity block swizzle: with round-robin workgroup->XCD dispatch (L%8),
// give each XCD a contiguous y-slab so an A-panel is fetched by ONE XCD, not 8.
// Valid when gridDim.y % 8 == 0 (all our grids); else identity.
__device__ __forceinline__ void xcd_swizzle(int& bx, int& by) {
  const int nbx = gridDim.x, nby = gridDim.y;
  if ((nby & 7) == 0) {
    const int L = blockIdx.y * nbx + blockIdx.x;
    const int xcd = L & 7, idx = L >> 3;
    bx = idx % nbx;
    by = (xcd * (nby >> 3)) + idx / nbx;
  } else {
    bx = blockIdx.x; by = blockIdx.y;
  }
}

// ---------------- elementwise f32 -> bf16 cast ----------------
__global__ void cast_f32_bf16(const float* __restrict__ in, unsigned short* __restrict__ out, long n4) {
  long i = (long)blockIdx.x * blockDim.x + threadIdx.x;
  const long stride = (long)gridDim.x * blockDim.x;
  for (; i < n4; i += stride) {
    float4 v = ((const float4*)in)[i];
    ushort4 o;
    o.x = f2b(v.x); o.y = f2b(v.y); o.z = f2b(v.z); o.w = f2b(v.w);
    ((ushort4*)out)[i] = o;
  }
}

// ---------------- transpose+cast: in[R,C] f32 -> out[C,R] bf16 ----------------
__global__ void transpose_cast(const float* __restrict__ in, unsigned short* __restrict__ out,
                               int R, int C) {
  __shared__ float t[32][33];
  const int lx = threadIdx.x & 31, ly = threadIdx.x >> 5;   // 32x8
  const int r0 = blockIdx.y * 32, c0 = blockIdx.x * 32;
#pragma unroll
  for (int i = 0; i < 32; i += 8)
    t[ly + i][lx] = in[(long)(r0 + ly + i) * C + (c0 + lx)];
  __syncthreads();
#pragma unroll
  for (int i = 0; i < 32; i += 8)
    out[(long)(c0 + ly + i) * R + (r0 + lx)] = f2b(t[lx][ly + i]);
}

// ---------------- MFMA GEMM: C[M,N] = A[M,K] @ Bt[N,K]^T, bf16 in, fp32 acc ----------------
// 128x128 tile, BK=64, 256 thr (4 waves in 2x2), XOR-swizzled LDS, global_load_lds w=16.
// EPI: 0 f32 | 1 silu->bf16 | 2 (*aux)->bf16 | 3 bf16 | 4 clip+-5,silu->bf16 | 6 0.1*v->bf16
template<int EPI>
__global__ __launch_bounds__(256)
void gemm_bt(const unsigned short* __restrict__ Ag, long sAz, int lda,
             const unsigned short* __restrict__ Bg, long sBz, int ldb,
             void* __restrict__ Cg, long sCz, int ldc,
             const unsigned short* __restrict__ Xg, long sXz, int ldx,
             int K)
{
  __shared__ __align__(16) short As[128*64];
  __shared__ __align__(16) short Bs[128*64];
  int bx, by; xcd_swizzle(bx, by);
  const int tid  = threadIdx.x;
  const int lane = tid & 63, wave = tid >> 6;
  const int q = lane >> 4, l15 = lane & 15, l7 = lane & 7;
  const int wm = wave & 1, wn = wave >> 1;

  const int arow = tid >> 3;                       // 0..31
  const int kc8  = ((tid & 7) ^ (arow & 7)) * 8;   // element offset within BK tile

  const short* Ap = (const short*)Ag + (long)blockIdx.z*sAz + (long)(by*128 + arow)*lda + kc8;
  const short* Bp = (const short*)Bg + (long)blockIdx.z*sBz + (long)(bx*128 + arow)*ldb + kc8;
  char* AsW = (char*)As + wave*1024;
  char* BsW = (char*)Bs + wave*1024;

  floatx4 acc[4][4] = {};

  for (int kt = 0; kt < K; kt += 64) {
    __syncthreads();
#pragma unroll
    for (int i = 0; i < 4; ++i) {
      __builtin_amdgcn_global_load_lds((glob_cvoid*)(Ap + (long)i*32*lda + kt),
                                       (lds_void*)(AsW + i*4096), 16, 0, 0);
      __builtin_amdgcn_global_load_lds((glob_cvoid*)(Bp + (long)i*32*ldb + kt),
                                       (lds_void*)(BsW + i*4096), 16, 0, 0);
    }
    __syncthreads();
#pragma unroll
    for (int s = 0; s < 2; ++s) {
      short8 af[4], bf[4];
      const int slotoff = ((s*4 + q) ^ l7) * 16;
#pragma unroll
      for (int i = 0; i < 4; ++i) {
        af[i] = *(const short8*)((const char*)As + (wm*64 + i*16 + l15)*128 + slotoff);
        bf[i] = *(const short8*)((const char*)Bs + (wn*64 + i*16 + l15)*128 + slotoff);
      }
#pragma unroll
      for (int i = 0; i < 4; ++i)
#pragma unroll
        for (int j = 0; j < 4; ++j)
          acc[i][j] = __builtin_amdgcn_mfma_f32_16x16x32_bf16(af[i], bf[j], acc[i][j], 0, 0, 0);
    }
  }

  const long cz = (long)blockIdx.z * sCz;
  const long xz = (long)blockIdx.z * sXz;
#pragma unroll
  for (int i = 0; i < 4; ++i)
#pragma unroll
    for (int j = 0; j < 4; ++j)
#pragma unroll
      for (int r = 0; r < 4; ++r) {
        const int row = by*128 + wm*64 + i*16 + q*4 + r;
        const int col = bx*128 + wn*64 + j*16 + l15;
        const long ci = cz + (long)row*ldc + col;
        float v = acc[i][j][r];
        if (EPI == 0) {
          ((float*)Cg)[ci] = v;
        } else if (EPI == 1) {
          v = v / (1.f + __expf(-v));
          ((unsigned short*)Cg)[ci] = f2b(v);
        } else if (EPI == 2) {
          float g = b2f(Xg[xz + (long)row*ldx + col]);
          ((unsigned short*)Cg)[ci] = f2b(v * g);
        } else if (EPI == 3) {
          ((unsigned short*)Cg)[ci] = f2b(v);
        } else if (EPI == 4) {
          v = fminf(fmaxf(v, -5.f), 5.f);
          v = v / (1.f + __expf(-v));
          ((unsigned short*)Cg)[ci] = f2b(v);
        } else if (EPI == 6) {
          ((unsigned short*)Cg)[ci] = f2b(0.1f * v);
        }
      }
}

// ---------------- fused final GEMM: out = hid@wdb^T + Fc@Wc'^T (Wc' pre-scaled 0.1) ----------------
__global__ __launch_bounds__(256)
void gemm_final(const unsigned short* __restrict__ hidp,
                const unsigned short* __restrict__ wdbp,
                const unsigned short* __restrict__ Fcp,
                const unsigned short* __restrict__ Wcp,
                float* __restrict__ outp)
{
  __shared__ __align__(16) short As[128*64];
  __shared__ __align__(16) short Bs[128*64];
  int bx, by; xcd_swizzle(bx, by);
  const int tid  = threadIdx.x;
  const int lane = tid & 63, wave = tid >> 6;
  const int q = lane >> 4, l15 = lane & 15, l7 = lane & 7;
  const int wm = wave & 1, wn = wave >> 1;
  const int arow = tid >> 3;
  const int kc8  = ((tid & 7) ^ (arow & 7)) * 8;
  char* AsW = (char*)As + wave*1024;
  char* BsW = (char*)Bs + wave*1024;

  floatx4 acc[4][4] = {};

  // phase 1: hid @ wdb^T, K = HH
  {
    const short* Ap = (const short*)hidp + (long)(by*128 + arow)*HH + kc8;
    const short* Bp = (const short*)wdbp + (long)(bx*128 + arow)*HH + kc8;
    for (int kt = 0; kt < HH; kt += 64) {
      __syncthreads();
#pragma unroll
      for (int i = 0; i < 4; ++i) {
        __builtin_amdgcn_global_load_lds((glob_cvoid*)(Ap + (long)i*32*HH + kt),
                                         (lds_void*)(AsW + i*4096), 16, 0, 0);
        __builtin_amdgcn_global_load_lds((glob_cvoid*)(Bp + (long)i*32*HH + kt),
                                         (lds_void*)(BsW + i*4096), 16, 0, 0);
      }
      __syncthreads();
#pragma unroll
      for (int s = 0; s < 2; ++s) {
        short8 af[4], bf[4];
        const int slotoff = ((s*4 + q) ^ l7) * 16;
#pragma unroll
        for (int i = 0; i < 4; ++i) {
          af[i] = *(const short8*)((const char*)As + (wm*64 + i*16 + l15)*128 + slotoff);
          bf[i] = *(const short8*)((const char*)Bs + (wn*64 + i*16 + l15)*128 + slotoff);
        }
#pragma unroll
        for (int i = 0; i < 4; ++i)
#pragma unroll
          for (int j = 0; j < 4; ++j)
            acc[i][j] = __builtin_amdgcn_mfma_f32_16x16x32_bf16(af[i], bf[j], acc[i][j], 0, 0, 0);
      }
    }
  }
  // phase 2: Fc @ Wc'^T, K = 256
  {
    const short* Ap = (const short*)Fcp + (long)(by*128 + arow)*256 + kc8;
    const short* Bp = (const short*)Wcp + (long)(bx*128 + arow)*256 + kc8;
    for (int kt = 0; kt < 256; kt += 64) {
      __syncthreads();
#pragma unroll
      for (int i = 0; i < 4; ++i) {
        __builtin_amdgcn_global_load_lds((glob_cvoid*)(Ap + (long)i*32*256 + kt),
                                         (lds_void*)(AsW + i*4096), 16, 0, 0);
        __builtin_amdgcn_global_load_lds((glob_cvoid*)(Bp + (long)i*32*256 + kt),
                                         (lds_void*)(BsW + i*4096), 16, 0, 0);
      }
      __syncthreads();
#pragma unroll
      for (int s = 0; s < 2; ++s) {
        short8 af[4], bf[4];
        const int slotoff = ((s*4 + q) ^ l7) * 16;
#pragma unroll
        for (int i = 0; i < 4; ++i) {
          af[i] = *(const short8*)((const char*)As + (wm*64 + i*16 + l15)*128 + slotoff);
          bf[i] = *(const short8*)((const char*)Bs + (wn*64 + i*16 + l15)*128 + slotoff);
        }
#pragma unroll
        for (int i = 0; i < 4; ++i)
#pragma unroll
          for (int j = 0; j < 4; ++j)
            acc[i][j] = __builtin_amdgcn_mfma_f32_16x16x32_bf16(af[i], bf[j], acc[i][j], 0, 0, 0);
      }
    }
  }

#pragma unroll
  for (int i = 0; i < 4; ++i)
#pragma unroll
    for (int j = 0; j < 4; ++j)
#pragma unroll
      for (int r = 0; r < 4; ++r) {
        const int row = by*128 + wm*64 + i*16 + q*4 + r;
        const int col = bx*128 + wn*64 + j*16 + l15;
        outp[(long)row*DD + col] = acc[i][j][r];
      }
}

// ---------------- LayerNorm over A=128 (one wave per row) ----------------
__global__ void ln_rows(const float* __restrict__ X, const float* __restrict__ g,
                        const float* __restrict__ b, unsigned short* __restrict__ lnout,
                        unsigned short* __restrict__ rawout, unsigned short* __restrict__ tout)
{
  const int lane = threadIdx.x & 63, wave = threadIdx.x >> 6;
  const long t = (long)blockIdx.x*4 + wave;
  const float* x = X + t*AA;
  float x0 = x[lane], x1 = x[lane + 64];
  float s = x0 + x1, s2 = x0*x0 + x1*x1;
#pragma unroll
  for (int m = 1; m < 64; m <<= 1) {
    s  += __shfl_xor(s, m, 64);
    s2 += __shfl_xor(s2, m, 64);
  }
  float mean = s * (1.f/AA);
  float inv  = rsqrtf(s2*(1.f/AA) - mean*mean + 1e-5f);
  float y0 = (x0 - mean)*inv*g[lane] + b[lane];
  float y1 = (x1 - mean)*inv*g[lane+64] + b[lane+64];
  lnout[t*AA + lane]      = f2b(y0);
  lnout[t*AA + lane + 64] = f2b(y1);
  if (rawout) { rawout[t*AA+lane] = f2b(x0); rawout[t*AA+lane+64] = f2b(x1); }
  if (tout) {
    const long bb = t >> 11, si = t & (SS-1);
    tout[bb*(long)AA*SS + (long)lane*SS + si]      = f2b(y0);
    tout[bb*(long)AA*SS + (long)(lane+64)*SS + si] = f2b(y1);
  }
}

// ---------------- per-token expert select (last positive wins) + LN ----------------
__global__ void expert_select_ln(const float* __restrict__ ew, const unsigned short* __restrict__ eall,
                                 const float* __restrict__ eg, const float* __restrict__ ebias,
                                 unsigned short* __restrict__ Fc)
{
  const int lane = threadIdx.x & 63, wave = threadIdx.x >> 6;
  const long t = (long)blockIdx.x*4 + wave;
  const float* w = ew + t*EE;
  int ie = -1;
#pragma unroll
  for (int i = 0; i < EE; ++i) if (w[i] > 0.f) ie = i;
  unsigned short o0 = 0, o1 = 0;
  if (ie >= 0) {
    float x0 = b2f(eall[t*(EE*AA) + ie*AA + lane]);
    float x1 = b2f(eall[t*(EE*AA) + ie*AA + lane + 64]);
    float s = x0 + x1, s2 = x0*x0 + x1*x1;
#pragma unroll
    for (int m = 1; m < 64; m <<= 1) { s += __shfl_xor(s, m, 64); s2 += __shfl_xor(s2, m, 64); }
    float mean = s * (1.f/AA);
    float inv  = rsqrtf(s2*(1.f/AA) - mean*mean + 1e-5f);
    o0 = f2b((x0-mean)*inv*eg[ie*AA+lane]    + ebias[ie*AA+lane]);
    o1 = f2b((x1-mean)*inv*eg[ie*AA+lane+64] + ebias[ie*AA+lane+64]);
  }
  Fc[t*256 + lane]      = o0;
  Fc[t*256 + lane + 64] = o1;
}

extern "C" void kernel_launch(void* const* d_in, const int* in_sizes, int n_in,
                              void* d_out, int out_size, void* d_ws, size_t ws_size,
                              hipStream_t stream)
{
  const float* x       = (const float*)d_in[0];
  const float* ew      = (const float*)d_in[1];
  const float* w_up    = (const float*)d_in[2];
  const float* w_gate  = (const float*)d_in[3];
  const float* w_down  = (const float*)d_in[4];
  const float* w_pre   = (const float*)d_in[5];
  const float* w_post  = (const float*)d_in[6];
  const float* an_g    = (const float*)d_in[7];
  const float* an_b    = (const float*)d_in[8];
  const float* w_aproj = (const float*)d_in[9];
  const float* w_exp   = (const float*)d_in[10];
  const float* eln_g   = (const float*)d_in[11];
  const float* eln_b   = (const float*)d_in[12];
  const float* w_eproj = (const float*)d_in[13];
  const float* w_out   = (const float*)d_in[14];

  char* ws = (char*)d_ws;
  size_t off = 0;
  auto take = [&](size_t bytes) { char* p = ws + off; off += (bytes + 255) & ~(size_t)255; return p; };

  // Sc (scores, 64MB) aliases xb (first 32MB) + eall (next 32MB): xb dead after the
  // pre-GEMM, eall dead after expert_select_ln — both strictly before the scores GEMM.
  unsigned short* Sc    = (unsigned short*)take((size_t)BB*SS*SS*2);
  unsigned short* xb    = Sc;
  unsigned short* eall  = (unsigned short*)((char*)Sc + (size_t)TOK*DD*2);
  unsigned short* hid   = (unsigned short*)take((size_t)TOK*HH*2);
  float*          pre   = (float*)take((size_t)TOK*AA*4);
  float*          postA = (float*)take((size_t)TOK*AA*4);
  unsigned short* Fc    = (unsigned short*)take((size_t)TOK*256*2);
  unsigned short* ain   = (unsigned short*)take((size_t)TOK*AA*2);
  unsigned short* ainT  = (unsigned short*)take((size_t)TOK*AA*2);
  unsigned short* aout  = (unsigned short*)take((size_t)TOK*AA*2);
  unsigned short* preb  = (unsigned short*)take((size_t)TOK*AA*2);
  unsigned short* wgb   = (unsigned short*)take((size_t)HH*DD*2);
  unsigned short* wub   = (unsigned short*)take((size_t)HH*DD*2);
  unsigned short* wdb   = (unsigned short*)take((size_t)DD*HH*2);
  unsigned short* wpostb= (unsigned short*)take((size_t)AA*HH*2);
  unsigned short* wpreb = (unsigned short*)take((size_t)AA*DD*2);
  unsigned short* wexpb = (unsigned short*)take((size_t)EE*AA*AA*2);
  unsigned short* Wc    = (unsigned short*)take((size_t)DD*256*2);
  (void)ws_size; (void)in_sizes; (void)n_in; (void)out_size;

  // Fold operands alias hid (hid is first written by the gate GEMM, which runs
  // strictly after the fold GEMM on this stream): w_out_bf16 (4MB) + eproj^T/aproj^T (1MB).
  unsigned short* woutb  = hid;                               // [1024,2048] bf16
  unsigned short* btT    = hid + (size_t)DD*HH;               // [2,128,2048] bf16
  unsigned short* eprojT = btT;
  unsigned short* aprojT = btT + (size_t)AA*HH;

  // casts
  cast_f32_bf16<<<1024, 256, 0, stream>>>(x,      xb,     (long)TOK*DD/4);
  cast_f32_bf16<<<256,  256, 0, stream>>>(w_gate, wgb,    (long)HH*DD/4);
  cast_f32_bf16<<<256,  256, 0, stream>>>(w_up,   wub,    (long)HH*DD/4);
  cast_f32_bf16<<<256,  256, 0, stream>>>(w_down, wdb,    (long)DD*HH/4);
  cast_f32_bf16<<<256,  256, 0, stream>>>(w_out,  woutb,  (long)DD*HH/4);
  cast_f32_bf16<<<64,   256, 0, stream>>>(w_post, wpostb, (long)AA*HH/4);
  cast_f32_bf16<<<32,   256, 0, stream>>>(w_pre,  wpreb,  (long)AA*DD/4);
  cast_f32_bf16<<<32,   256, 0, stream>>>(w_exp,  wexpb,  (long)EE*AA*AA/4);

  // transpose+cast the fold B operands: [H,A] f32 -> [A,H] bf16
  transpose_cast<<<dim3(AA/32, HH/32), 256, 0, stream>>>(w_eproj, eprojT, HH, AA);
  transpose_cast<<<dim3(AA/32, HH/32), 256, 0, stream>>>(w_aproj, aprojT, HH, AA);

  // folded matrices via batched MFMA GEMM, pre-scaled by 0.1 (EPI 6):
  // z=0: 0.1*w_out@w_eproj -> Wc[:,0:128], z=1: 0.1*w_down@w_aproj -> Wc[:,128:256]
  gemm_bt<6><<<dim3(1, DD/128, 2), 256, 0, stream>>>(
      woutb, (long)(wdb - woutb), HH,
      eprojT, (long)AA*HH, HH,
      Wc, AA, 256, nullptr, 0, 0, HH);

  // gate (silu) then up (*gate), in place into hid
  gemm_bt<1><<<dim3(HH/128, TOK/128, 1), 256, 0, stream>>>(xb,0,DD, wgb,0,DD, hid,0,HH, nullptr,0,0, DD);
  gemm_bt<2><<<dim3(HH/128, TOK/128, 1), 256, 0, stream>>>(xb,0,DD, wub,0,DD, hid,0,HH, hid,0,HH, DD);

  // pre = x @ w_pre^T (fp32), then LN -> adapt_in (+ raw bf16 + transposed copy)
  gemm_bt<0><<<dim3(1, TOK/128, 1), 256, 0, stream>>>(xb,0,DD, wpreb,0,DD, pre,0,AA, nullptr,0,0, DD);
  ln_rows<<<TOK/4, 256, 0, stream>>>(pre, an_g, an_b, ain, preb, ainT);

  // all-expert mix + per-token select/LN -> Fc[:,0:128]
  gemm_bt<3><<<dim3((EE*AA)/128, TOK/128, 1), 256, 0, stream>>>(preb,0,AA, wexpb,0,AA, eall,0,EE*AA, nullptr,0,0, AA);
  expert_select_ln<<<TOK/4, 256, 0, stream>>>(ew, eall, eln_g, eln_b, Fc);

  // adapt_out = LN(hidden @ w_post^T)
  gemm_bt<0><<<dim3(1, TOK/128, 1), 256, 0, stream>>>(hid,0,HH, wpostb,0,HH, postA,0,AA, nullptr,0,0, HH);
  ln_rows<<<TOK/4, 256, 0, stream>>>(postA, an_g, an_b, aout, nullptr, nullptr);

  // scores: Sc[z] = silu(clip(ain[z] @ aout[z]^T))   (K = A = 128)
  gemm_bt<4><<<dim3(SS/128, SS/128, BB), 256, 0, stream>>>(ain,(long)SS*AA,AA, aout,(long)SS*AA,AA,
                                                           Sc,(long)SS*SS,SS, nullptr,0,0, AA);
  // adapt: Fc[:,128:256] = Sc[z] @ ainT[z]^T
  gemm_bt<3><<<dim3(1, SS/128, BB), 256, 0, stream>>>(Sc,(long)SS*SS,SS, ainT,(long)AA*SS,SS,
                                                      Fc+AA,(long)SS*256,256, nullptr,0,0, SS);
  // out = hid@wdb^T + Fc@Wc'^T  (fp32, Wc' pre-scaled by 0.1)
  gemm_final<<<dim3(DD/128, TOK/128, 1), 256, 0, stream>>>(hid, wdb, Fc, Wc, (float*)d_out);
}

// Round 5
// 602.908 us; speedup vs baseline: 1.1929x; 1.0838x over previous
//
#include <hip/hip_runtime.h>

#define TOK 16384
#define DD 1024
#define HH 2048
#define AA 128
#define EE 8
#define SS 2048
#define BB 8

typedef __attribute__((ext_vector_type(8))) short short8;
typedef __attribute__((ext_vector_type(4))) float floatx4;

__device__ __forceinline__ unsigned short f2b(float f) {
  unsigned u = __float_as_uint(f);
  u += 0x7fff + ((u >> 16) & 1);          // RNE
  return (unsigned short)(u >> 16);
}
__device__ __forceinline__ float b2f(unsigned short h) {
  return __uint_as_float(((unsigned)h) << 16);
}

// XCD-affinity block swizzle: with round-robin workgroup->XCD dispatch (L%8),
// give each XCD a contiguous y-slab so an A-panel is fetched by ONE XCD, not 8.
__device__ __forceinline__ void xcd_swizzle(int& bx, int& by) {
  const int nbx = gridDim.x, nby = gridDim.y;
  if ((nby & 7) == 0) {
    const int L = blockIdx.y * nbx + blockIdx.x;
    const int xcd = L & 7, idx = L >> 3;
    bx = idx % nbx;
    by = (xcd * (nby >> 3)) + idx / nbx;
  } else {
    bx = blockIdx.x; by = blockIdx.y;
  }
}

// ---- pipelined K-loop: global->VGPR prefetch overlaps MFMA; barriers need no vmcnt drain ----
// LDS tile 128 rows x 64 k (single-buffered, XOR-swizzled). Ap/Bp pre-offset to (row panel, kc8).
__device__ __forceinline__ void kloop_pipe(const short* Ap, int lda, const short* Bp, int ldb,
                                           short* As, short* Bs, int K,
                                           int tid, int q, int l15, int l7, int wm, int wn,
                                           floatx4 (*acc)[4])
{
  short8 pa[4], pb[4];
#pragma unroll
  for (int i = 0; i < 4; ++i) {
    pa[i] = *(const short8*)(Ap + (long)i*32*lda);
    pb[i] = *(const short8*)(Bp + (long)i*32*ldb);
  }
  for (int kt = 0; kt < K; kt += 64) {
    // stage current tile regs -> LDS (vmcnt wait for prefetch loads lands here,
    // after the previous tile's full compute phase)
#pragma unroll
    for (int i = 0; i < 4; ++i) {
      *(short8*)((char*)As + i*4096 + tid*16) = pa[i];
      *(short8*)((char*)Bs + i*4096 + tid*16) = pb[i];
    }
    __syncthreads();                       // lgkm drain only — no LDS-bound vmem outstanding
    if (kt + 64 < K) {                     // issue next-tile loads; stay in flight over compute
#pragma unroll
      for (int i = 0; i < 4; ++i) {
        pa[i] = *(const short8*)(Ap + (long)i*32*lda + kt + 64);
        pb[i] = *(const short8*)(Bp + (long)i*32*ldb + kt + 64);
      }
    }
#pragma unroll
    for (int s = 0; s < 2; ++s) {
      short8 af[4], bf[4];
      const int slotoff = ((s*4 + q) ^ l7) * 16;
#pragma unroll
      for (int i = 0; i < 4; ++i) {
        af[i] = *(const short8*)((const char*)As + (wm*64 + i*16 + l15)*128 + slotoff);
        bf[i] = *(const short8*)((const char*)Bs + (wn*64 + i*16 + l15)*128 + slotoff);
      }
#pragma unroll
      for (int i = 0; i < 4; ++i)
#pragma unroll
        for (int j = 0; j < 4; ++j)
          acc[i][j] = __builtin_amdgcn_mfma_f32_16x16x32_bf16(af[i], bf[j], acc[i][j], 0, 0, 0);
    }
    __syncthreads();                       // all reads of this tile done before next ds_write
  }
}

// ---------------- elementwise f32 -> bf16 cast ----------------
__global__ void cast_f32_bf16(const float* __restrict__ in, unsigned short* __restrict__ out, long n4) {
  long i = (long)blockIdx.x * blockDim.x + threadIdx.x;
  const long stride = (long)gridDim.x * blockDim.x;
  for (; i < n4; i += stride) {
    float4 v = ((const float4*)in)[i];
    ushort4 o;
    o.x = f2b(v.x); o.y = f2b(v.y); o.z = f2b(v.z); o.w = f2b(v.w);
    ((ushort4*)out)[i] = o;
  }
}

// ---------------- transpose+cast: in[R,C] f32 -> out[C,R] bf16 ----------------
__global__ void transpose_cast(const float* __restrict__ in, unsigned short* __restrict__ out,
                               int R, int C) {
  __shared__ float t[32][33];
  const int lx = threadIdx.x & 31, ly = threadIdx.x >> 5;   // 32x8
  const int r0 = blockIdx.y * 32, c0 = blockIdx.x * 32;
#pragma unroll
  for (int i = 0; i < 32; i += 8)
    t[ly + i][lx] = in[(long)(r0 + ly + i) * C + (c0 + lx)];
  __syncthreads();
#pragma unroll
  for (int i = 0; i < 32; i += 8)
    out[(long)(c0 + ly + i) * R + (r0 + lx)] = f2b(t[lx][ly + i]);
}

// ---------------- MFMA GEMM: C[M,N] = A[M,K] @ Bt[N,K]^T, bf16 in, fp32 acc ----------------
// 128x128 tile, BK=64, 256 thr (4 waves 2x2), XOR-swizzled LDS, pipelined K-loop.
// EPI: 0 f32 | 1 silu->bf16 | 2 (*aux)->bf16 | 3 bf16 | 4 clip+-5,silu->bf16 | 6 0.1*v->bf16
template<int EPI>
__global__ __launch_bounds__(256)
void gemm_bt(const unsigned short* __restrict__ Ag, long sAz, int lda,
             const unsigned short* __restrict__ Bg, long sBz, int ldb,
             void* __restrict__ Cg, long sCz, int ldc,
             const unsigned short* __restrict__ Xg, long sXz, int ldx,
             int K)
{
  __shared__ __align__(16) short As[128*64];
  __shared__ __align__(16) short Bs[128*64];
  int bx, by; xcd_swizzle(bx, by);
  const int tid  = threadIdx.x;
  const int lane = tid & 63, wave = tid >> 6;
  const int q = lane >> 4, l15 = lane & 15, l7 = lane & 7;
  const int wm = wave & 1, wn = wave >> 1;

  const int arow = tid >> 3;                       // 0..31
  const int kc8  = ((tid & 7) ^ (arow & 7)) * 8;   // XOR-swizzled k-chunk

  const short* Ap = (const short*)Ag + (long)blockIdx.z*sAz + (long)(by*128 + arow)*lda + kc8;
  const short* Bp = (const short*)Bg + (long)blockIdx.z*sBz + (long)(bx*128 + arow)*ldb + kc8;

  floatx4 acc[4][4] = {};
  kloop_pipe(Ap, lda, Bp, ldb, As, Bs, K, tid, q, l15, l7, wm, wn, acc);

  const long cz = (long)blockIdx.z * sCz;
  const long xz = (long)blockIdx.z * sXz;
#pragma unroll
  for (int i = 0; i < 4; ++i)
#pragma unroll
    for (int j = 0; j < 4; ++j)
#pragma unroll
      for (int r = 0; r < 4; ++r) {
        const int row = by*128 + wm*64 + i*16 + q*4 + r;
        const int col = bx*128 + wn*64 + j*16 + l15;
        const long ci = cz + (long)row*ldc + col;
        float v = acc[i][j][r];
        if (EPI == 0) {
          ((float*)Cg)[ci] = v;
        } else if (EPI == 1) {
          v = v / (1.f + __expf(-v));
          ((unsigned short*)Cg)[ci] = f2b(v);
        } else if (EPI == 2) {
          float g = b2f(Xg[xz + (long)row*ldx + col]);
          ((unsigned short*)Cg)[ci] = f2b(v * g);
        } else if (EPI == 3) {
          ((unsigned short*)Cg)[ci] = f2b(v);
        } else if (EPI == 4) {
          v = fminf(fmaxf(v, -5.f), 5.f);
          v = v / (1.f + __expf(-v));
          ((unsigned short*)Cg)[ci] = f2b(v);
        } else if (EPI == 6) {
          ((unsigned short*)Cg)[ci] = f2b(0.1f * v);
        }
      }
}

// ---------------- fused final GEMM: out = hid@wdb^T + Fc@Wc'^T (Wc' pre-scaled 0.1) ----------------
__global__ __launch_bounds__(256)
void gemm_final(const unsigned short* __restrict__ hidp,
                const unsigned short* __restrict__ wdbp,
                const unsigned short* __restrict__ Fcp,
                const unsigned short* __restrict__ Wcp,
                float* __restrict__ outp)
{
  __shared__ __align__(16) short As[128*64];
  __shared__ __align__(16) short Bs[128*64];
  int bx, by; xcd_swizzle(bx, by);
  const int tid  = threadIdx.x;
  const int lane = tid & 63, wave = tid >> 6;
  const int q = lane >> 4, l15 = lane & 15, l7 = lane & 7;
  const int wm = wave & 1, wn = wave >> 1;
  const int arow = tid >> 3;
  const int kc8  = ((tid & 7) ^ (arow & 7)) * 8;

  floatx4 acc[4][4] = {};

  // phase 1: hid @ wdb^T, K = HH
  kloop_pipe((const short*)hidp + (long)(by*128 + arow)*HH + kc8, HH,
             (const short*)wdbp + (long)(bx*128 + arow)*HH + kc8, HH,
             As, Bs, HH, tid, q, l15, l7, wm, wn, acc);
  // phase 2: Fc @ Wc'^T, K = 256
  kloop_pipe((const short*)Fcp + (long)(by*128 + arow)*256 + kc8, 256,
             (const short*)Wcp + (long)(bx*128 + arow)*256 + kc8, 256,
             As, Bs, 256, tid, q, l15, l7, wm, wn, acc);

#pragma unroll
  for (int i = 0; i < 4; ++i)
#pragma unroll
    for (int j = 0; j < 4; ++j)
#pragma unroll
      for (int r = 0; r < 4; ++r) {
        const int row = by*128 + wm*64 + i*16 + q*4 + r;
        const int col = bx*128 + wn*64 + j*16 + l15;
        outp[(long)row*DD + col] = acc[i][j][r];
      }
}

// ---------------- LayerNorm over A=128 (one wave per row) ----------------
__global__ void ln_rows(const float* __restrict__ X, const float* __restrict__ g,
                        const float* __restrict__ b, unsigned short* __restrict__ lnout,
                        unsigned short* __restrict__ rawout, unsigned short* __restrict__ tout)
{
  const int lane = threadIdx.x & 63, wave = threadIdx.x >> 6;
  const long t = (long)blockIdx.x*4 + wave;
  const float* x = X + t*AA;
  float x0 = x[lane], x1 = x[lane + 64];
  float s = x0 + x1, s2 = x0*x0 + x1*x1;
#pragma unroll
  for (int m = 1; m < 64; m <<= 1) {
    s  += __shfl_xor(s, m, 64);
    s2 += __shfl_xor(s2, m, 64);
  }
  float mean = s * (1.f/AA);
  float inv  = rsqrtf(s2*(1.f/AA) - mean*mean + 1e-5f);
  float y0 = (x0 - mean)*inv*g[lane] + b[lane];
  float y1 = (x1 - mean)*inv*g[lane+64] + b[lane+64];
  lnout[t*AA + lane]      = f2b(y0);
  lnout[t*AA + lane + 64] = f2b(y1);
  if (rawout) { rawout[t*AA+lane] = f2b(x0); rawout[t*AA+lane+64] = f2b(x1); }
  if (tout) {
    const long bb = t >> 11, si = t & (SS-1);
    tout[bb*(long)AA*SS + (long)lane*SS + si]      = f2b(y0);
    tout[bb*(long)AA*SS + (long)(lane+64)*SS + si] = f2b(y1);
  }
}

// ---------------- per-token expert select (last positive wins) + LN ----------------
__global__ void expert_select_ln(const float* __restrict__ ew, const unsigned short* __restrict__ eall,
                                 const float* __restrict__ eg, const float* __restrict__ ebias,
                                 unsigned short* __restrict__ Fc)
{
  const int lane = threadIdx.x & 63, wave = threadIdx.x >> 6;
  const long t = (long)blockIdx.x*4 + wave;
  const float* w = ew + t*EE;
  int ie = -1;
#pragma unroll
  for (int i = 0; i < EE; ++i) if (w[i] > 0.f) ie = i;
  unsigned short o0 = 0, o1 = 0;
  if (ie >= 0) {
    float x0 = b2f(eall[t*(EE*AA) + ie*AA + lane]);
    float x1 = b2f(eall[t*(EE*AA) + ie*AA + lane + 64]);
    float s = x0 + x1, s2 = x0*x0 + x1*x1;
#pragma unroll
    for (int m = 1; m < 64; m <<= 1) { s += __shfl_xor(s, m, 64); s2 += __shfl_xor(s2, m, 64); }
    float mean = s * (1.f/AA);
    float inv  = rsqrtf(s2*(1.f/AA) - mean*mean + 1e-5f);
    o0 = f2b((x0-mean)*inv*eg[ie*AA+lane]    + ebias[ie*AA+lane]);
    o1 = f2b((x1-mean)*inv*eg[ie*AA+lane+64] + ebias[ie*AA+lane+64]);
  }
  Fc[t*256 + lane]      = o0;
  Fc[t*256 + lane + 64] = o1;
}

extern "C" void kernel_launch(void* const* d_in, const int* in_sizes, int n_in,
                              void* d_out, int out_size, void* d_ws, size_t ws_size,
                              hipStream_t stream)
{
  const float* x       = (const float*)d_in[0];
  const float* ew      = (const float*)d_in[1];
  const float* w_up    = (const float*)d_in[2];
  const float* w_gate  = (const float*)d_in[3];
  const float* w_down  = (const float*)d_in[4];
  const float* w_pre   = (const float*)d_in[5];
  const float* w_post  = (const float*)d_in[6];
  const float* an_g    = (const float*)d_in[7];
  const float* an_b    = (const float*)d_in[8];
  const float* w_aproj = (const float*)d_in[9];
  const float* w_exp   = (const float*)d_in[10];
  const float* eln_g   = (const float*)d_in[11];
  const float* eln_b   = (const float*)d_in[12];
  const float* w_eproj = (const float*)d_in[13];
  const float* w_out   = (const float*)d_in[14];

  char* ws = (char*)d_ws;
  size_t off = 0;
  auto take = [&](size_t bytes) { char* p = ws + off; off += (bytes + 255) & ~(size_t)255; return p; };

  // Sc (scores, 64MB) aliases xb (first 32MB) + eall (next 32MB): xb dead after the
  // pre-GEMM, eall dead after expert_select_ln — both strictly before the scores GEMM.
  unsigned short* Sc    = (unsigned short*)take((size_t)BB*SS*SS*2);
  unsigned short* xb    = Sc;
  unsigned short* eall  = (unsigned short*)((char*)Sc + (size_t)TOK*DD*2);
  unsigned short* hid   = (unsigned short*)take((size_t)TOK*HH*2);
  float*          pre   = (float*)take((size_t)TOK*AA*4);
  float*          postA = (float*)take((size_t)TOK*AA*4);
  unsigned short* Fc    = (unsigned short*)take((size_t)TOK*256*2);
  unsigned short* ain   = (unsigned short*)take((size_t)TOK*AA*2);
  unsigned short* ainT  = (unsigned short*)take((size_t)TOK*AA*2);
  unsigned short* aout  = (unsigned short*)take((size_t)TOK*AA*2);
  unsigned short* preb  = (unsigned short*)take((size_t)TOK*AA*2);
  unsigned short* wgb   = (unsigned short*)take((size_t)HH*DD*2);
  unsigned short* wub   = (unsigned short*)take((size_t)HH*DD*2);
  unsigned short* wdb   = (unsigned short*)take((size_t)DD*HH*2);
  unsigned short* wpostb= (unsigned short*)take((size_t)AA*HH*2);
  unsigned short* wpreb = (unsigned short*)take((size_t)AA*DD*2);
  unsigned short* wexpb = (unsigned short*)take((size_t)EE*AA*AA*2);
  unsigned short* Wc    = (unsigned short*)take((size_t)DD*256*2);
  (void)ws_size; (void)in_sizes; (void)n_in; (void)out_size;

  // Fold operands alias hid (hid is first written by the gate GEMM, which runs
  // strictly after the fold GEMM on this stream): w_out_bf16 (4MB) + eproj^T/aproj^T (1MB).
  unsigned short* woutb  = hid;                               // [1024,2048] bf16
  unsigned short* btT    = hid + (size_t)DD*HH;               // [2,128,2048] bf16
  unsigned short* eprojT = btT;
  unsigned short* aprojT = btT + (size_t)AA*HH;

  // casts
  cast_f32_bf16<<<1024, 256, 0, stream>>>(x,      xb,     (long)TOK*DD/4);
  cast_f32_bf16<<<256,  256, 0, stream>>>(w_gate, wgb,    (long)HH*DD/4);
  cast_f32_bf16<<<256,  256, 0, stream>>>(w_up,   wub,    (long)HH*DD/4);
  cast_f32_bf16<<<256,  256, 0, stream>>>(w_down, wdb,    (long)DD*HH/4);
  cast_f32_bf16<<<256,  256, 0, stream>>>(w_out,  woutb,  (long)DD*HH/4);
  cast_f32_bf16<<<64,   256, 0, stream>>>(w_post, wpostb, (long)AA*HH/4);
  cast_f32_bf16<<<32,   256, 0, stream>>>(w_pre,  wpreb,  (long)AA*DD/4);
  cast_f32_bf16<<<32,   256, 0, stream>>>(w_exp,  wexpb,  (long)EE*AA*AA/4);

  // transpose+cast the fold B operands: [H,A] f32 -> [A,H] bf16
  transpose_cast<<<dim3(AA/32, HH/32), 256, 0, stream>>>(w_eproj, eprojT, HH, AA);
  transpose_cast<<<dim3(AA/32, HH/32), 256, 0, stream>>>(w_aproj, aprojT, HH, AA);

  // folded matrices via batched MFMA GEMM, pre-scaled by 0.1 (EPI 6):
  // z=0: 0.1*w_out@w_eproj -> Wc[:,0:128], z=1: 0.1*w_down@w_aproj -> Wc[:,128:256]
  gemm_bt<6><<<dim3(1, DD/128, 2), 256, 0, stream>>>(
      woutb, (long)(wdb - woutb), HH,
      eprojT, (long)AA*HH, HH,
      Wc, AA, 256, nullptr, 0, 0, HH);

  // gate (silu) then up (*gate), in place into hid
  gemm_bt<1><<<dim3(HH/128, TOK/128, 1), 256, 0, stream>>>(xb,0,DD, wgb,0,DD, hid,0,HH, nullptr,0,0, DD);
  gemm_bt<2><<<dim3(HH/128, TOK/128, 1), 256, 0, stream>>>(xb,0,DD, wub,0,DD, hid,0,HH, hid,0,HH, DD);

  // pre = x @ w_pre^T (fp32), then LN -> adapt_in (+ raw bf16 + transposed copy)
  gemm_bt<0><<<dim3(1, TOK/128, 1), 256, 0, stream>>>(xb,0,DD, wpreb,0,DD, pre,0,AA, nullptr,0,0, DD);
  ln_rows<<<TOK/4, 256, 0, stream>>>(pre, an_g, an_b, ain, preb, ainT);

  // all-expert mix + per-token select/LN -> Fc[:,0:128]
  gemm_bt<3><<<dim3((EE*AA)/128, TOK/128, 1), 256, 0, stream>>>(preb,0,AA, wexpb,0,AA, eall,0,EE*AA, nullptr,0,0, AA);
  expert_select_ln<<<TOK/4, 256, 0, stream>>>(ew, eall, eln_g, eln_b, Fc);

  // adapt_out = LN(hidden @ w_post^T)
  gemm_bt<0><<<dim3(1, TOK/128, 1), 256, 0, stream>>>(hid,0,HH, wpostb,0,HH, postA,0,AA, nullptr,0,0, HH);
  ln_rows<<<TOK/4, 256, 0, stream>>>(postA, an_g, an_b, aout, nullptr, nullptr);

  // scores: Sc[z] = silu(clip(ain[z] @ aout[z]^T))   (K = A = 128)
  gemm_bt<4><<<dim3(SS/128, SS/128, BB), 256, 0, stream>>>(ain,(long)SS*AA,AA, aout,(long)SS*AA,AA,
                                                           Sc,(long)SS*SS,SS, nullptr,0,0, AA);
  // adapt: Fc[:,128:256] = Sc[z] @ ainT[z]^T
  gemm_bt<3><<<dim3(1, SS/128, BB), 256, 0, stream>>>(Sc,(long)SS*SS,SS, ainT,(long)AA*SS,SS,
                                                      Fc+AA,(long)SS*256,256, nullptr,0,0, SS);
  // out = hid@wdb^T + Fc@Wc'^T  (fp32, Wc' pre-scaled by 0.1)
  gemm_final<<<dim3(DD/128, TOK/128, 1), 256, 0, stream>>>(hid, wdb, Fc, Wc, (float*)d_out);
}